// Round 10
// baseline (205.039 us; speedup 1.0000x reference)
//
#include <hip/hip_runtime.h>

typedef __attribute__((ext_vector_type(8))) short bf16x8;
typedef __attribute__((ext_vector_type(4))) short s16x4;
typedef __attribute__((ext_vector_type(4))) float f32x4;
typedef __attribute__((ext_vector_type(4))) int   i32x4;

#define MFMA16 __builtin_amdgcn_mfma_f32_16x16x32_bf16

#define B_ 64
#define N_ 512
#define D_ 128

__device__ __forceinline__ unsigned short f2bf(float f) {
  unsigned u = __builtin_bit_cast(unsigned, f);
  u += 0x7fffu + ((u >> 16) & 1u);          // round-to-nearest-even
  return (unsigned short)(u >> 16);
}
__device__ __forceinline__ int packbf2(float lo, float hi) {
  return (int)((unsigned)f2bf(lo) | ((unsigned)f2bf(hi) << 16));
}

// ---------------- prep: W -> bf16; fold t*log2e into Wq/bq ----------------
__global__ void prep_w(const float* __restrict__ Wk, const float* __restrict__ Wq,
                       const float* __restrict__ bq, const float* __restrict__ tptr,
                       short* __restrict__ wkb, short* __restrict__ wqb,
                       float* __restrict__ bqs) {
  const float sc = tptr[0] * 1.4426950408889634f;   // t * log2(e)
  int i = blockIdx.x * 256 + threadIdx.x;
  if (i < D_ * D_) { wkb[i] = (short)f2bf(Wk[i]); wqb[i] = (short)f2bf(Wq[i] * sc); }
  if (i < D_) bqs[i] = bq[i] * sc;
}

// ---------------- projections ----------------
// k = h@Wk^T+bk (row-major), q' = (h@Wq^T+bq)*t*log2e (row-major),
// vt = k^T stored CHUNK-TILED: vt[b][ch][d][key%32] -> the 128x32 V^T block
// one attention chunk needs is 8KB contiguous.
__global__ __launch_bounds__(256, 2) void proj_kernel(
    const float* __restrict__ h1, const float* __restrict__ h2,
    const short* __restrict__ wkb, const short* __restrict__ wqb,
    const float* __restrict__ bk, const float* __restrict__ bqs,
    short* __restrict__ k1, short* __restrict__ k2,
    short* __restrict__ q1, short* __restrict__ q2,
    short* __restrict__ v1t, short* __restrict__ v2t) {
  const int wave = threadIdx.x >> 6, lane = threadIdx.x & 63;
  const int c = lane & 15, g = lane >> 4;
  const int rw = blockIdx.x * 128 + wave * 32;
  const int inp = rw >> 15;
  const int loc = rw & 32767;
  const int b = loc >> 9, n0 = loc & 511;
  const float* __restrict__ h = inp ? h2 : h1;
  short* __restrict__ kout = inp ? k2 : k1;
  short* __restrict__ qout = inp ? q2 : q1;
  short* __restrict__ vt   = inp ? v2t : v1t;

  bf16x8 xf[2][4];
#pragma unroll
  for (int mt = 0; mt < 2; ++mt) {
    const float* hr = h + (long)(loc + mt * 16 + c) * D_;
#pragma unroll
    for (int kk = 0; kk < 4; ++kk) {
      f32x4 lo = *(const f32x4*)(hr + kk * 32 + g * 8);
      f32x4 hi = *(const f32x4*)(hr + kk * 32 + g * 8 + 4);
      bf16x8 v;
      v[0] = (short)f2bf(lo[0]); v[1] = (short)f2bf(lo[1]);
      v[2] = (short)f2bf(lo[2]); v[3] = (short)f2bf(lo[3]);
      v[4] = (short)f2bf(hi[0]); v[5] = (short)f2bf(hi[1]);
      v[6] = (short)f2bf(hi[2]); v[7] = (short)f2bf(hi[3]);
      xf[mt][kk] = v;
    }
  }

#pragma unroll
  for (int et = 0; et < 8; ++et) {
    bf16x8 wkf[4], wqf[4];
    const short* wkr = wkb + (et * 16 + c) * D_;
    const short* wqr = wqb + (et * 16 + c) * D_;
#pragma unroll
    for (int kk = 0; kk < 4; ++kk) {
      wkf[kk] = *(const bf16x8*)(wkr + kk * 32 + g * 8);
      wqf[kk] = *(const bf16x8*)(wqr + kk * 32 + g * 8);
    }
    f32x4 ak[2], aq[2], at[2];
#pragma unroll
    for (int mt = 0; mt < 2; ++mt) {
      ak[mt] = (f32x4){0.f, 0.f, 0.f, 0.f};
      aq[mt] = (f32x4){0.f, 0.f, 0.f, 0.f};
      at[mt] = (f32x4){0.f, 0.f, 0.f, 0.f};
    }
#pragma unroll
    for (int kk = 0; kk < 4; ++kk) {
#pragma unroll
      for (int mt = 0; mt < 2; ++mt) {
        ak[mt] = MFMA16(wkf[kk], xf[mt][kk], ak[mt], 0, 0, 0);
        aq[mt] = MFMA16(wqf[kk], xf[mt][kk], aq[mt], 0, 0, 0);
        at[mt] = MFMA16(xf[mt][kk], wkf[kk], at[mt], 0, 0, 0);
      }
    }
    f32x4 bkv = *(const f32x4*)(bk + et * 16 + g * 4);
    f32x4 bqv = *(const f32x4*)(bqs + et * 16 + g * 4);
    float bks = bk[et * 16 + c];
#pragma unroll
    for (int mt = 0; mt < 2; ++mt) {
      s16x4 pk, pq, pt;
#pragma unroll
      for (int j = 0; j < 4; ++j) {
        pk[j] = (short)f2bf(ak[mt][j] + bkv[j]);
        pq[j] = (short)f2bf(aq[mt][j] + bqv[j]);
        pt[j] = (short)f2bf(at[mt][j] + bks);
      }
      long row = (long)(loc + mt * 16 + c);
      *(s16x4*)(kout + row * D_ + et * 16 + g * 4) = pk;
      *(s16x4*)(qout + row * D_ + et * 16 + g * 4) = pq;
      *(s16x4*)(vt + (long)b * 65536 + (n0 >> 5) * 4096 +
                (et * 16 + c) * 32 + mt * 16 + g * 4) = pt;
    }
  }
}

// ---------------- attention: 2 waves/job split over key-chunks ----------------
// 2048 blocks x 128 thr (2 waves) = 4096 waves = 16/CU = the 4-waves/SIMD
// VGPR-128 capacity. Block = job (bd, qt) = 32 q-rows; wave w handles chunks
// w, w+2, ... (fixed-max softmax makes chunk partials pure sums). End: one
// LDS exchange (each wave writes the OTHER wave's d-half + its l-partials),
// one __syncthreads, each wave merges + stores its own d-half.
// bid = qt*8 + (bd&7) + 128*(bd>>3): jobs of one (b,dir) share an XCD but
// spread over 16 CU slots. Chunk body: no barriers, K dbuf (+2), tiled V.
__global__ __launch_bounds__(128, 4) void attn_kernel(
    const short* __restrict__ k1, const short* __restrict__ k2,
    const short* __restrict__ q1, const short* __restrict__ q2,
    const short* __restrict__ v1t, const short* __restrict__ v2t,
    const int* __restrict__ len1, const int* __restrict__ len2,
    float* __restrict__ out) {
  __shared__ f32x4 lds_o[2][2][4][64];     // [writer wave][t][i][lane]
  __shared__ float lds_l[2][2][64];        // [writer wave][t][lane]
  const int tid = threadIdx.x;
  const int wave = tid >> 6, lane = tid & 63;
  const int c = lane & 15, g = lane >> 4;
  const int bid = blockIdx.x;
  const int bd = (bid & 7) | ((bid >> 7) << 3);         // 0..127
  const int qt = (bid >> 3) & 15;                       // 0..15
  const int dir = bd >> 6, b = bd & 63;
  const short* __restrict__ qp = dir ? q2 : q1;
  const short* __restrict__ kp = dir ? k1 : k2;
  const short* __restrict__ vp = dir ? v1t : v2t;
  const int lk = dir ? len1[b] : len2[b];
  const int lq = dir ? len2[b] : len1[b];
  float* __restrict__ o = out + (long)dir * B_ * N_ * D_;
  const int q0 = qt * 32;

  // ---- invalid job: zero 32 rows with both waves, done ----
  if (q0 >= lq) {
    f32x4 z = (f32x4){0.f, 0.f, 0.f, 0.f};
    f32x4* op = (f32x4*)(o + ((long)(b * N_ + q0)) * D_);
#pragma unroll
    for (int i = 0; i < 8; ++i) op[i * 128 + tid] = z;
    return;
  }

  const char* kbase = (const char*)(kp + (long)b * N_ * D_);   // [512][256B]
  const short* vbase = vp + (long)b * 65536;                    // [16 ch][128][32]

  // Q fragments (lane=q-row); pre-scaled by t*log2e at prep
  bf16x8 qf[2][4];
#pragma unroll
  for (int t = 0; t < 2; ++t) {
    const short* qrow = qp + ((long)(b * N_ + q0 + t * 16 + c)) * D_;
#pragma unroll
    for (int kk = 0; kk < 4; ++kk) qf[t][kk] = *(const bf16x8*)(qrow + kk * 32 + g * 8);
  }

  f32x4 oacc[2][8];
#pragma unroll
  for (int t = 0; t < 2; ++t)
#pragma unroll
    for (int dt = 0; dt < 8; ++dt) oacc[t][dt] = (f32x4){0.f, 0.f, 0.f, 0.f};
  float lp[2] = {0.f, 0.f};                // per-lane partial row-sums

  const int srcA = c + ((g & 1) << 5);
  const int srcB = srcA + 16;
  const bool lowhalf = (g < 2);
  const int nch = (lk + 31) >> 5;          // 1..16 chunks of 32 keys

  auto loadk = [&](bf16x8 (&kf)[2][4], int ch) {
#pragma unroll
    for (int tl = 0; tl < 2; ++tl) {
      const char* base = kbase + (ch * 32 + tl * 16 + c) * 256;
#pragma unroll
      for (int kk = 0; kk < 4; ++kk)
        kf[tl][kk] = *(const bf16x8*)(base + kk * 64 + g * 16);
    }
  };

  auto body = [&](bf16x8 (&kfc)[2][4], bf16x8 (&kfn)[2][4], int ch) {
    // V^T fragments from the tiled 8KB chunk block
    const short* vchunk = vbase + ch * 4096;
    bf16x8 vt[8];
#pragma unroll
    for (int dt = 0; dt < 8; ++dt)
      vt[dt] = *(const bf16x8*)(vchunk + (dt * 16 + c) * 32 + g * 8);
    __builtin_amdgcn_sched_barrier(0);     // pin V issue before compute

    // QK^T (exp2-domain scores); kfc landed two chunks ago
    f32x4 sv[2][2];
#pragma unroll
    for (int tl = 0; tl < 2; ++tl) {
      f32x4 a0 = (f32x4){0.f, 0.f, 0.f, 0.f};
      f32x4 a1 = (f32x4){0.f, 0.f, 0.f, 0.f};
#pragma unroll
      for (int kk = 0; kk < 4; ++kk) {
        a0 = MFMA16(kfc[tl][kk], qf[0][kk], a0, 0, 0, 0);
        a1 = MFMA16(kfc[tl][kk], qf[1][kk], a1, 0, 0, 0);
      }
      sv[0][tl] = a0; sv[1][tl] = a1;
    }

    // prefetch this wave's next chunk (+2); pin issue before softmax/PV
    if (ch + 2 < nch) loadk(kfn, ch + 2);
    __builtin_amdgcn_sched_barrier(0);

    const bool lastch = (ch == nch - 1);
    bf16x8 pf[2];
#pragma unroll
    for (int t = 0; t < 2; ++t) {
      if (lastch) {
#pragma unroll
        for (int tl = 0; tl < 2; ++tl) {
          const int node = ch * 32 + tl * 16 + g * 4;
#pragma unroll
          for (int j = 0; j < 4; ++j)
            if (node + j >= lk) sv[t][tl][j] = -1e9f;
        }
      }
      float sum = 0.f;
#pragma unroll
      for (int tl = 0; tl < 2; ++tl)
#pragma unroll
        for (int j = 0; j < 4; ++j) {
          float p = exp2f(sv[t][tl][j]);   // fixed-max: no subtraction
          sv[t][tl][j] = p;
          sum += p;
        }
      lp[t] += sum;

      // pack P -> bf16 B-fragment
      int a0 = packbf2(sv[t][0][0], sv[t][0][1]);
      int a1 = packbf2(sv[t][0][2], sv[t][0][3]);
      int b0 = packbf2(sv[t][1][0], sv[t][1][1]);
      int b1 = packbf2(sv[t][1][2], sv[t][1][3]);
      int xa0 = __shfl(a0, srcA), xb0 = __shfl(b0, srcA);
      int xa1 = __shfl(a1, srcA), xb1 = __shfl(b1, srcA);
      int ya0 = __shfl(a0, srcB), yb0 = __shfl(b0, srcB);
      int ya1 = __shfl(a1, srcB), yb1 = __shfl(b1, srcB);
      i32x4 ui;
      ui[0] = lowhalf ? xa0 : xb0;
      ui[1] = lowhalf ? xa1 : xb1;
      ui[2] = lowhalf ? ya0 : yb0;
      ui[3] = lowhalf ? ya1 : yb1;
      pf[t] = __builtin_bit_cast(bf16x8, ui);
    }

    // PV
#pragma unroll
    for (int dt = 0; dt < 8; ++dt) {
      oacc[0][dt] = MFMA16(vt[dt], pf[0], oacc[0][dt], 0, 0, 0);
      oacc[1][dt] = MFMA16(vt[dt], pf[1], oacc[1][dt], 0, 0, 0);
    }
  };

  // wave w processes chunks w, w+2, ...
  {
    bf16x8 kfA[2][4], kfB[2][4];
    int ch = wave;
    if (ch < nch) {
      loadk(kfA, ch);
      while (true) {
        body(kfA, kfB, ch);
        ch += 2;
        if (ch >= nch) break;
        body(kfB, kfA, ch);
        ch += 2;
        if (ch >= nch) break;
      }
    }
  }

  // ---- merge the two waves' partials via LDS ----
  const int ow = wave ^ 1;
#pragma unroll
  for (int t = 0; t < 2; ++t) {
#pragma unroll
    for (int i = 0; i < 4; ++i)
      lds_o[wave][t][i][lane] = oacc[t][ow * 4 + i];   // give partner its d-half
    lds_l[wave][t][lane] = lp[t];
  }
  __syncthreads();

#pragma unroll
  for (int t = 0; t < 2; ++t) {
    float lsum = lp[t] + lds_l[ow][t][lane];
    lsum += __shfl_xor(lsum, 16);
    lsum += __shfl_xor(lsum, 32);
    const float rinv = 1.0f / lsum;
    const int qg = q0 + t * 16 + c;
    const bool valid = qg < lq;
    float* orow = o + ((long)(b * N_ + qg)) * D_;
#pragma unroll
    for (int i = 0; i < 4; ++i) {
      const int dt = wave * 4 + i;
      f32x4 mine = oacc[t][dt];
      f32x4 oth = lds_o[ow][t][i][lane];
      f32x4 vo;
#pragma unroll
      for (int j = 0; j < 4; ++j) vo[j] = valid ? (mine[j] + oth[j]) * rinv : 0.0f;
      *(f32x4*)(orow + dt * 16 + g * 4) = vo;
    }
  }
}

extern "C" void kernel_launch(void* const* d_in, const int* in_sizes, int n_in,
                              void* d_out, int out_size, void* d_ws, size_t ws_size,
                              hipStream_t stream) {
  const float* h1 = (const float*)d_in[0];
  const float* h2 = (const float*)d_in[1];
  const float* Wk = (const float*)d_in[2];
  const float* bk = (const float*)d_in[3];
  const float* Wq = (const float*)d_in[4];
  const float* bq = (const float*)d_in[5];
  const float* t  = (const float*)d_in[6];
  const int* len1 = (const int*)d_in[7];
  const int* len2 = (const int*)d_in[8];

  char* ws = (char*)d_ws;
  const size_t SZ = (size_t)B_ * N_ * D_ * 2;
  short* k1  = (short*)(ws + 0 * SZ);
  short* k2  = (short*)(ws + 1 * SZ);
  short* q1  = (short*)(ws + 2 * SZ);
  short* q2  = (short*)(ws + 3 * SZ);
  short* v1t = (short*)(ws + 4 * SZ);
  short* v2t = (short*)(ws + 5 * SZ);
  short* wkb = (short*)(ws + 6 * SZ);
  short* wqb = (short*)(ws + 6 * SZ + D_ * D_ * 2);
  float* bqs = (float*)(ws + 6 * SZ + 2 * D_ * D_ * 2);

  prep_w<<<64, 256, 0, stream>>>(Wk, Wq, bq, t, wkb, wqb, bqs);
  proj_kernel<<<512, 256, 0, stream>>>(h1, h2, wkb, wqb, bk, bqs,
                                       k1, k2, q1, q2, v1t, v2t);
  attn_kernel<<<2048, 128, 0, stream>>>(k1, k2, q1, q2, v1t, v2t,
                                        len1, len2, (float*)d_out);
}

// Round 11
// 84.674 us; speedup vs baseline: 2.4215x; 2.4215x over previous
//
#include <hip/hip_runtime.h>

typedef __attribute__((ext_vector_type(8))) short bf16x8;
typedef __attribute__((ext_vector_type(4))) short s16x4;
typedef __attribute__((ext_vector_type(4))) float f32x4;
typedef __attribute__((ext_vector_type(4))) int   i32x4;

#define MFMA16 __builtin_amdgcn_mfma_f32_16x16x32_bf16

#define B_ 64
#define N_ 512
#define D_ 128

__device__ __forceinline__ unsigned short f2bf(float f) {
  unsigned u = __builtin_bit_cast(unsigned, f);
  u += 0x7fffu + ((u >> 16) & 1u);          // round-to-nearest-even
  return (unsigned short)(u >> 16);
}
__device__ __forceinline__ int packbf2(float lo, float hi) {
  return (int)((unsigned)f2bf(lo) | ((unsigned)f2bf(hi) << 16));
}

// ---------------- prep: W -> bf16; fold t*log2e into Wq/bq ----------------
__global__ void prep_w(const float* __restrict__ Wk, const float* __restrict__ Wq,
                       const float* __restrict__ bq, const float* __restrict__ tptr,
                       short* __restrict__ wkb, short* __restrict__ wqb,
                       float* __restrict__ bqs) {
  const float sc = tptr[0] * 1.4426950408889634f;   // t * log2(e)
  int i = blockIdx.x * 256 + threadIdx.x;
  if (i < D_ * D_) { wkb[i] = (short)f2bf(Wk[i]); wqb[i] = (short)f2bf(Wq[i] * sc); }
  if (i < D_) bqs[i] = bq[i] * sc;
}

// ---------------- projections ----------------
// k = h@Wk^T+bk (row-major), q' = (h@Wq^T+bq)*t*log2e (row-major),
// vt = k^T stored CHUNK-TILED: vt[b][ch][d][key%32] -> the 128x32 V^T block
// one attention chunk needs is 8KB contiguous.
__global__ __launch_bounds__(256, 2) void proj_kernel(
    const float* __restrict__ h1, const float* __restrict__ h2,
    const short* __restrict__ wkb, const short* __restrict__ wqb,
    const float* __restrict__ bk, const float* __restrict__ bqs,
    short* __restrict__ k1, short* __restrict__ k2,
    short* __restrict__ q1, short* __restrict__ q2,
    short* __restrict__ v1t, short* __restrict__ v2t) {
  const int wave = threadIdx.x >> 6, lane = threadIdx.x & 63;
  const int c = lane & 15, g = lane >> 4;
  const int rw = blockIdx.x * 128 + wave * 32;
  const int inp = rw >> 15;
  const int loc = rw & 32767;
  const int b = loc >> 9, n0 = loc & 511;
  const float* __restrict__ h = inp ? h2 : h1;
  short* __restrict__ kout = inp ? k2 : k1;
  short* __restrict__ qout = inp ? q2 : q1;
  short* __restrict__ vt   = inp ? v2t : v1t;

  bf16x8 xf[2][4];
#pragma unroll
  for (int mt = 0; mt < 2; ++mt) {
    const float* hr = h + (long)(loc + mt * 16 + c) * D_;
#pragma unroll
    for (int kk = 0; kk < 4; ++kk) {
      f32x4 lo = *(const f32x4*)(hr + kk * 32 + g * 8);
      f32x4 hi = *(const f32x4*)(hr + kk * 32 + g * 8 + 4);
      bf16x8 v;
      v[0] = (short)f2bf(lo[0]); v[1] = (short)f2bf(lo[1]);
      v[2] = (short)f2bf(lo[2]); v[3] = (short)f2bf(lo[3]);
      v[4] = (short)f2bf(hi[0]); v[5] = (short)f2bf(hi[1]);
      v[6] = (short)f2bf(hi[2]); v[7] = (short)f2bf(hi[3]);
      xf[mt][kk] = v;
    }
  }

#pragma unroll
  for (int et = 0; et < 8; ++et) {
    bf16x8 wkf[4], wqf[4];
    const short* wkr = wkb + (et * 16 + c) * D_;
    const short* wqr = wqb + (et * 16 + c) * D_;
#pragma unroll
    for (int kk = 0; kk < 4; ++kk) {
      wkf[kk] = *(const bf16x8*)(wkr + kk * 32 + g * 8);
      wqf[kk] = *(const bf16x8*)(wqr + kk * 32 + g * 8);
    }
    f32x4 ak[2], aq[2], at[2];
#pragma unroll
    for (int mt = 0; mt < 2; ++mt) {
      ak[mt] = (f32x4){0.f, 0.f, 0.f, 0.f};
      aq[mt] = (f32x4){0.f, 0.f, 0.f, 0.f};
      at[mt] = (f32x4){0.f, 0.f, 0.f, 0.f};
    }
#pragma unroll
    for (int kk = 0; kk < 4; ++kk) {
#pragma unroll
      for (int mt = 0; mt < 2; ++mt) {
        ak[mt] = MFMA16(wkf[kk], xf[mt][kk], ak[mt], 0, 0, 0);
        aq[mt] = MFMA16(wqf[kk], xf[mt][kk], aq[mt], 0, 0, 0);
        at[mt] = MFMA16(xf[mt][kk], wkf[kk], at[mt], 0, 0, 0);
      }
    }
    f32x4 bkv = *(const f32x4*)(bk + et * 16 + g * 4);
    f32x4 bqv = *(const f32x4*)(bqs + et * 16 + g * 4);
    float bks = bk[et * 16 + c];
#pragma unroll
    for (int mt = 0; mt < 2; ++mt) {
      s16x4 pk, pq, pt;
#pragma unroll
      for (int j = 0; j < 4; ++j) {
        pk[j] = (short)f2bf(ak[mt][j] + bkv[j]);
        pq[j] = (short)f2bf(aq[mt][j] + bqv[j]);
        pt[j] = (short)f2bf(at[mt][j] + bks);
      }
      long row = (long)(loc + mt * 16 + c);
      *(s16x4*)(kout + row * D_ + et * 16 + g * 4) = pk;
      *(s16x4*)(qout + row * D_ + et * 16 + g * 4) = pq;
      *(s16x4*)(vt + (long)b * 65536 + (n0 >> 5) * 4096 +
                (et * 16 + c) * 32 + mt * 16 + g * 4) = pt;
    }
  }
}

// ---------------- attention: 2 waves/job split over key-chunks ----------------
// 2048 blocks x 128 thr (2 waves). Block = job (bd, qt) = 32 q-rows; wave w
// handles chunks w, w+2, ... (fixed-max softmax makes chunk partials pure
// sums). End: one LDS exchange + one __syncthreads + merged store.
// __launch_bounds__(128, 2): 256-VGPR budget -- body fits in ~128 (R8/R9),
// giving 4 waves/SIMD naturally. (128,4) forced a 64-VGPR cap -> 313MB of
// scratch spills (R10 post-mortem); never pin min-waves at the cliff edge.
// bid = qt*8 + (bd&7) + 128*(bd>>3): jobs of one (b,dir) share an XCD but
// spread over 16 CU slots. Chunk body: no barriers, K dbuf (+2), tiled V.
__global__ __launch_bounds__(128, 2) void attn_kernel(
    const short* __restrict__ k1, const short* __restrict__ k2,
    const short* __restrict__ q1, const short* __restrict__ q2,
    const short* __restrict__ v1t, const short* __restrict__ v2t,
    const int* __restrict__ len1, const int* __restrict__ len2,
    float* __restrict__ out) {
  __shared__ f32x4 lds_o[2][2][4][64];     // [writer wave][t][i][lane]
  __shared__ float lds_l[2][2][64];        // [writer wave][t][lane]
  const int tid = threadIdx.x;
  const int wave = tid >> 6, lane = tid & 63;
  const int c = lane & 15, g = lane >> 4;
  const int bid = blockIdx.x;
  const int bd = (bid & 7) | ((bid >> 7) << 3);         // 0..127
  const int qt = (bid >> 3) & 15;                       // 0..15
  const int dir = bd >> 6, b = bd & 63;
  const short* __restrict__ qp = dir ? q2 : q1;
  const short* __restrict__ kp = dir ? k1 : k2;
  const short* __restrict__ vp = dir ? v1t : v2t;
  const int lk = dir ? len1[b] : len2[b];
  const int lq = dir ? len2[b] : len1[b];
  float* __restrict__ o = out + (long)dir * B_ * N_ * D_;
  const int q0 = qt * 32;

  // ---- invalid job: zero 32 rows with both waves, done ----
  if (q0 >= lq) {
    f32x4 z = (f32x4){0.f, 0.f, 0.f, 0.f};
    f32x4* op = (f32x4*)(o + ((long)(b * N_ + q0)) * D_);
#pragma unroll
    for (int i = 0; i < 8; ++i) op[i * 128 + tid] = z;
    return;
  }

  const char* kbase = (const char*)(kp + (long)b * N_ * D_);   // [512][256B]
  const short* vbase = vp + (long)b * 65536;                    // [16 ch][128][32]

  // Q fragments (lane=q-row); pre-scaled by t*log2e at prep
  bf16x8 qf[2][4];
#pragma unroll
  for (int t = 0; t < 2; ++t) {
    const short* qrow = qp + ((long)(b * N_ + q0 + t * 16 + c)) * D_;
#pragma unroll
    for (int kk = 0; kk < 4; ++kk) qf[t][kk] = *(const bf16x8*)(qrow + kk * 32 + g * 8);
  }

  f32x4 oacc[2][8];
#pragma unroll
  for (int t = 0; t < 2; ++t)
#pragma unroll
    for (int dt = 0; dt < 8; ++dt) oacc[t][dt] = (f32x4){0.f, 0.f, 0.f, 0.f};
  float lp[2] = {0.f, 0.f};                // per-lane partial row-sums

  const int srcA = c + ((g & 1) << 5);
  const int srcB = srcA + 16;
  const bool lowhalf = (g < 2);
  const int nch = (lk + 31) >> 5;          // 1..16 chunks of 32 keys

  auto loadk = [&](bf16x8 (&kf)[2][4], int ch) {
#pragma unroll
    for (int tl = 0; tl < 2; ++tl) {
      const char* base = kbase + (ch * 32 + tl * 16 + c) * 256;
#pragma unroll
      for (int kk = 0; kk < 4; ++kk)
        kf[tl][kk] = *(const bf16x8*)(base + kk * 64 + g * 16);
    }
  };

  auto body = [&](bf16x8 (&kfc)[2][4], bf16x8 (&kfn)[2][4], int ch) {
    // V^T fragments from the tiled 8KB chunk block
    const short* vchunk = vbase + ch * 4096;
    bf16x8 vt[8];
#pragma unroll
    for (int dt = 0; dt < 8; ++dt)
      vt[dt] = *(const bf16x8*)(vchunk + (dt * 16 + c) * 32 + g * 8);
    __builtin_amdgcn_sched_barrier(0);     // pin V issue before compute

    // QK^T (exp2-domain scores); kfc landed two chunks ago
    f32x4 sv[2][2];
#pragma unroll
    for (int tl = 0; tl < 2; ++tl) {
      f32x4 a0 = (f32x4){0.f, 0.f, 0.f, 0.f};
      f32x4 a1 = (f32x4){0.f, 0.f, 0.f, 0.f};
#pragma unroll
      for (int kk = 0; kk < 4; ++kk) {
        a0 = MFMA16(kfc[tl][kk], qf[0][kk], a0, 0, 0, 0);
        a1 = MFMA16(kfc[tl][kk], qf[1][kk], a1, 0, 0, 0);
      }
      sv[0][tl] = a0; sv[1][tl] = a1;
    }

    // prefetch this wave's next chunk (+2); pin issue before softmax/PV
    if (ch + 2 < nch) loadk(kfn, ch + 2);
    __builtin_amdgcn_sched_barrier(0);

    const bool lastch = (ch == nch - 1);
    bf16x8 pf[2];
#pragma unroll
    for (int t = 0; t < 2; ++t) {
      if (lastch) {
#pragma unroll
        for (int tl = 0; tl < 2; ++tl) {
          const int node = ch * 32 + tl * 16 + g * 4;
#pragma unroll
          for (int j = 0; j < 4; ++j)
            if (node + j >= lk) sv[t][tl][j] = -1e9f;
        }
      }
      float sum = 0.f;
#pragma unroll
      for (int tl = 0; tl < 2; ++tl)
#pragma unroll
        for (int j = 0; j < 4; ++j) {
          float p = exp2f(sv[t][tl][j]);   // fixed-max: no subtraction
          sv[t][tl][j] = p;
          sum += p;
        }
      lp[t] += sum;

      // pack P -> bf16 B-fragment
      int a0 = packbf2(sv[t][0][0], sv[t][0][1]);
      int a1 = packbf2(sv[t][0][2], sv[t][0][3]);
      int b0 = packbf2(sv[t][1][0], sv[t][1][1]);
      int b1 = packbf2(sv[t][1][2], sv[t][1][3]);
      int xa0 = __shfl(a0, srcA), xb0 = __shfl(b0, srcA);
      int xa1 = __shfl(a1, srcA), xb1 = __shfl(b1, srcA);
      int ya0 = __shfl(a0, srcB), yb0 = __shfl(b0, srcB);
      int ya1 = __shfl(a1, srcB), yb1 = __shfl(b1, srcB);
      i32x4 ui;
      ui[0] = lowhalf ? xa0 : xb0;
      ui[1] = lowhalf ? xa1 : xb1;
      ui[2] = lowhalf ? ya0 : yb0;
      ui[3] = lowhalf ? ya1 : yb1;
      pf[t] = __builtin_bit_cast(bf16x8, ui);
    }

    // PV
#pragma unroll
    for (int dt = 0; dt < 8; ++dt) {
      oacc[0][dt] = MFMA16(vt[dt], pf[0], oacc[0][dt], 0, 0, 0);
      oacc[1][dt] = MFMA16(vt[dt], pf[1], oacc[1][dt], 0, 0, 0);
    }
  };

  // wave w processes chunks w, w+2, ...
  {
    bf16x8 kfA[2][4], kfB[2][4];
    int ch = wave;
    if (ch < nch) {
      loadk(kfA, ch);
      while (true) {
        body(kfA, kfB, ch);
        ch += 2;
        if (ch >= nch) break;
        body(kfB, kfA, ch);
        ch += 2;
        if (ch >= nch) break;
      }
    }
  }

  // ---- merge the two waves' partials via LDS ----
  const int ow = wave ^ 1;
#pragma unroll
  for (int t = 0; t < 2; ++t) {
#pragma unroll
    for (int i = 0; i < 4; ++i)
      lds_o[wave][t][i][lane] = oacc[t][ow * 4 + i];   // give partner its d-half
    lds_l[wave][t][lane] = lp[t];
  }
  __syncthreads();

#pragma unroll
  for (int t = 0; t < 2; ++t) {
    float lsum = lp[t] + lds_l[ow][t][lane];
    lsum += __shfl_xor(lsum, 16);
    lsum += __shfl_xor(lsum, 32);
    const float rinv = 1.0f / lsum;
    const int qg = q0 + t * 16 + c;
    const bool valid = qg < lq;
    float* orow = o + ((long)(b * N_ + qg)) * D_;
#pragma unroll
    for (int i = 0; i < 4; ++i) {
      const int dt = wave * 4 + i;
      f32x4 mine = oacc[t][dt];
      f32x4 oth = lds_o[ow][t][i][lane];
      f32x4 vo;
#pragma unroll
      for (int j = 0; j < 4; ++j) vo[j] = valid ? (mine[j] + oth[j]) * rinv : 0.0f;
      *(f32x4*)(orow + dt * 16 + g * 4) = vo;
    }
  }
}

extern "C" void kernel_launch(void* const* d_in, const int* in_sizes, int n_in,
                              void* d_out, int out_size, void* d_ws, size_t ws_size,
                              hipStream_t stream) {
  const float* h1 = (const float*)d_in[0];
  const float* h2 = (const float*)d_in[1];
  const float* Wk = (const float*)d_in[2];
  const float* bk = (const float*)d_in[3];
  const float* Wq = (const float*)d_in[4];
  const float* bq = (const float*)d_in[5];
  const float* t  = (const float*)d_in[6];
  const int* len1 = (const int*)d_in[7];
  const int* len2 = (const int*)d_in[8];

  char* ws = (char*)d_ws;
  const size_t SZ = (size_t)B_ * N_ * D_ * 2;
  short* k1  = (short*)(ws + 0 * SZ);
  short* k2  = (short*)(ws + 1 * SZ);
  short* q1  = (short*)(ws + 2 * SZ);
  short* q2  = (short*)(ws + 3 * SZ);
  short* v1t = (short*)(ws + 4 * SZ);
  short* v2t = (short*)(ws + 5 * SZ);
  short* wkb = (short*)(ws + 6 * SZ);
  short* wqb = (short*)(ws + 6 * SZ + D_ * D_ * 2);
  float* bqs = (float*)(ws + 6 * SZ + 2 * D_ * D_ * 2);

  prep_w<<<64, 256, 0, stream>>>(Wk, Wq, bq, t, wkb, wqb, bqs);
  proj_kernel<<<512, 256, 0, stream>>>(h1, h2, wkb, wqb, bk, bqs,
                                       k1, k2, q1, q2, v1t, v2t);
  attn_kernel<<<2048, 128, 0, stream>>>(k1, k2, q1, q2, v1t, v2t,
                                        len1, len2, (float*)d_out);
}